// Round 2
// baseline (4192.820 us; speedup 1.0000x reference)
//
#include <hip/hip_runtime.h>
#include <hip/hip_bf16.h>

#define B_   32
#define H_   128
#define W_   128
#define HW_  16384
#define C1_  128

// ---------------- zero stats ----------------
__global__ void zero_k(float* p) { p[threadIdx.x] = 0.f; }

// ---------------- gaussian splat: vertical pass (writes into out's gauss region) ----
__global__ __launch_bounds__(256) void gauss_v(const float* __restrict__ jmap,
                                               float* __restrict__ gtmp,
                                               const float* __restrict__ ga,
                                               const float* __restrict__ gb) {
    __shared__ float k1[255];
    float a = ga[0] / (gb[0] * gb[0]);
    for (int i = threadIdx.x; i < 255; i += 256) {
        float d = (float)(i - 127);
        k1[i] = expf(a * d * d);
    }
    __syncthreads();
    int b = blockIdx.y;
    int y = blockIdx.x * 2 + (threadIdx.x >> 7);
    int x = threadIdx.x & 127;
    const float* m = jmap + (size_t)b * HW_;
    float s = 0.f;
    for (int yy = 0; yy < H_; ++yy) {
        float mv = m[yy * W_ + x];
        s += (mv == 1.0f) ? k1[yy - y + 127] : 0.f;
    }
    gtmp[(size_t)b * HW_ + y * W_ + x] = s;
}

// ---------------- gaussian splat: horizontal pass + finalize (in-place on gtmp) ----
__global__ __launch_bounds__(256) void gauss_h(const float* __restrict__ jmap,
                                               float* __restrict__ gtmp,
                                               const float* __restrict__ ga,
                                               const float* __restrict__ gb) {
    __shared__ float k1[255];
    __shared__ float row[256];
    float a = ga[0] / (gb[0] * gb[0]);
    for (int i = threadIdx.x; i < 255; i += 256) {
        float d = (float)(i - 127);
        k1[i] = expf(a * d * d);
    }
    int b = blockIdx.y;
    int y0 = blockIdx.x * 2;
    int tid = threadIdx.x;
    row[tid] = gtmp[(size_t)b * HW_ + (y0 + (tid >> 7)) * W_ + (tid & 127)];
    __syncthreads();
    int y = y0 + (tid >> 7);
    int x = tid & 127;
    int base = (tid >> 7) * 128;
    float s = 0.f;
    for (int xx = 0; xx < W_; ++xx)
        s += k1[xx - x + 127] * row[base + xx];
    float g = jmap[(size_t)b * HW_ + y * W_ + x] + s;
    g = (g <= 0.05f) ? 0.f : fminf(g, 1.0f);
    gtmp[(size_t)b * HW_ + y * W_ + x] = g;
}

// ---------------- conv1 stats only (no activation storage) ----------------
// grid (16 co-groups of 8, 32 b), 256 threads
__global__ __launch_bounds__(256) void conv1stats_k(const float* __restrict__ out5,
                                                    const float* __restrict__ w1,
                                                    const float* __restrict__ b1,
                                                    float* __restrict__ sum1,
                                                    float* __restrict__ sq1) {
    int cg = blockIdx.x;
    int b  = blockIdx.y;
    int tid = threadIdx.x;
    __shared__ float wsh[8][18];
    __shared__ float bsh[8];
    __shared__ float red[256];
    for (int i = tid; i < 144; i += 256) wsh[i / 18][i % 18] = w1[cg * 8 * 18 + i];
    if (tid < 8) bsh[tid] = b1[cg * 8 + tid];
    __syncthreads();
    float ls[8], lq[8];
    #pragma unroll
    for (int i = 0; i < 8; ++i) { ls[i] = 0.f; lq[i] = 0.f; }
    const float* in0 = out5 + (size_t)b * 5 * HW_;
    const float* in1 = in0 + HW_;
    for (int pos = tid; pos < HW_; pos += 256) {
        int y = pos >> 7, x = pos & 127;
        float v0[9], v1[9];
        #pragma unroll
        for (int ky = 0; ky < 3; ++ky)
            #pragma unroll
            for (int kx = 0; kx < 3; ++kx) {
                int yy = y + ky - 1, xx = x + kx - 1;
                bool ok = ((unsigned)yy < 128u) && ((unsigned)xx < 128u);
                v0[ky * 3 + kx] = ok ? in0[yy * W_ + xx] : 0.f;
                v1[ky * 3 + kx] = ok ? in1[yy * W_ + xx] : 0.f;
            }
        #pragma unroll
        for (int i = 0; i < 8; ++i) {
            float a = bsh[i];
            #pragma unroll
            for (int k = 0; k < 9; ++k) a += v0[k] * wsh[i][k] + v1[k] * wsh[i][9 + k];
            ls[i] += a; lq[i] += a * a;
        }
    }
    for (int i = 0; i < 8; ++i) {
        red[tid] = ls[i]; __syncthreads();
        for (int s = 128; s > 0; s >>= 1) { if (tid < s) red[tid] += red[tid + s]; __syncthreads(); }
        if (tid == 0) atomicAdd(&sum1[cg * 8 + i], red[0]);
        __syncthreads();
        red[tid] = lq[i]; __syncthreads();
        for (int s = 128; s > 0; s >>= 1) { if (tid < s) red[tid] += red[tid + s]; __syncthreads(); }
        if (tid == 0) atomicAdd(&sq1[cg * 8 + i], red[0]);
        __syncthreads();
    }
}

// ---------------- BN params: s = g/sqrt(var+eps), t = beta - s*mean ----------------
__global__ void bnp_k(const float* __restrict__ sum, const float* __restrict__ sq,
                      const float* __restrict__ gamma, const float* __restrict__ beta,
                      float* __restrict__ s, float* __restrict__ t) {
    int c = threadIdx.x;
    const float N = (float)(B_ * HW_);
    float m = sum[c] / N;
    float v = sq[c] / N - m * m;
    float sc = gamma[c] / sqrtf(v + 1e-5f);
    s[c] = sc;
    t[c] = beta[c] - sc * m;
}

// ---------------- conv2: recompute conv1+BN1+ReLU on the fly, 3x3 128->128, +stats ----
// block: 256 thr, tile 32co x (8 rows x 32 cols); thread: 4co x (2x4) spatial
__global__ __launch_bounds__(256) void conv2_k(const float* __restrict__ out5,
                                               const float* __restrict__ w1,
                                               const float* __restrict__ b1,
                                               const float* __restrict__ s1,
                                               const float* __restrict__ t1,
                                               const float* __restrict__ w2,
                                               const float* __restrict__ b2,
                                               __hip_bfloat16* __restrict__ y2,
                                               float* __restrict__ sum2,
                                               float* __restrict__ sq2) {
    const int co_t = blockIdx.x & 3;
    const int xt   = blockIdx.x >> 2;   // 0..3
    const int yt   = blockIdx.y;        // 0..15
    const int b    = blockIdx.z;
    const int x0 = xt * 32, y0 = yt * 8;
    const int tid = threadIdx.x;
    const int cog = tid >> 5;           // 0..7
    const int sp  = tid & 31;
    const int ry  = (sp >> 3) * 2;      // 0,2,4,6
    const int rx  = (sp & 7) * 4;       // 0..28

    __shared__ float inraw[2][12][36];
    __shared__ float w1f[128][18];
    __shared__ float b1sh[128], s1sh[128], t1sh[128];
    __shared__ float tile[16][10][36];
    __shared__ float wsh[32][16][9];
    __shared__ float redS[32], redQ[32];

    // one-time staging: raw input tile (2ch, halo 2) + conv1 params
    for (int idx = tid; idx < 864; idx += 256) {
        int ch = idx / 432;
        int rem = idx - ch * 432;
        int rr = rem / 36, c2 = rem - rr * 36;
        int gy = y0 + rr - 2, gx = x0 + c2 - 2;
        float v = 0.f;
        if ((unsigned)gy < 128u && (unsigned)gx < 128u)
            v = out5[((size_t)b * 5 + ch) * HW_ + gy * W_ + gx];
        inraw[ch][rr][c2] = v;
    }
    for (int idx = tid; idx < 2304; idx += 256) w1f[idx / 18][idx % 18] = w1[idx];
    if (tid < 128) { b1sh[tid] = b1[tid]; s1sh[tid] = s1[tid]; t1sh[tid] = t1[tid]; }

    float acc[4][2][4];
    #pragma unroll
    for (int i = 0; i < 4; ++i)
        #pragma unroll
        for (int r = 0; r < 2; ++r)
            #pragma unroll
            for (int c = 0; c < 4; ++c) acc[i][r][c] = 0.f;

    for (int cc = 0; cc < 8; ++cc) {
        const int cib = cc * 16;
        __syncthreads();  // first iter: covers staging; later: protects tile reuse
        // recompute conv1+BN1+ReLU for this ci-slab (10x34 with conv2 halo)
        for (int idx = tid; idx < 16 * 10 * 34; idx += 256) {
            int ci  = idx / 340;
            int rem = idx - ci * 340;
            int r   = rem / 34;
            int c   = rem - r * 34;
            int gy = y0 + r - 1, gx = x0 + c - 1;
            float v = 0.f;
            if ((unsigned)gy < 128u && (unsigned)gx < 128u) {
                const float* wp = w1f[cib + ci];
                float a = b1sh[cib + ci];
                #pragma unroll
                for (int ky = 0; ky < 3; ++ky)
                    #pragma unroll
                    for (int kx = 0; kx < 3; ++kx)
                        a += inraw[0][r + ky][c + kx] * wp[ky * 3 + kx]
                           + inraw[1][r + ky][c + kx] * wp[9 + ky * 3 + kx];
                v = fmaxf(fmaf(s1sh[cib + ci], a, t1sh[cib + ci]), 0.f);
            }
            tile[ci][r][c] = v;
        }
        for (int idx = tid; idx < 32 * 16 * 9; idx += 256) {
            int co_l = idx / 144;
            int rem  = idx - co_l * 144;
            int ci_l = rem / 9;
            int k    = rem - ci_l * 9;
            wsh[co_l][ci_l][k] = w2[(size_t)(co_t * 32 + co_l) * 1152 + (cib + ci_l) * 9 + k];
        }
        __syncthreads();
        for (int ci = 0; ci < 16; ++ci) {
            float iv[4][6];
            #pragma unroll
            for (int r = 0; r < 4; ++r)
                #pragma unroll
                for (int c = 0; c < 6; ++c) iv[r][c] = tile[ci][ry + r][rx + c];
            #pragma unroll
            for (int i = 0; i < 4; ++i) {
                #pragma unroll
                for (int ky = 0; ky < 3; ++ky)
                    #pragma unroll
                    for (int kx = 0; kx < 3; ++kx) {
                        float wv = wsh[cog * 4 + i][ci][ky * 3 + kx];
                        #pragma unroll
                        for (int r = 0; r < 2; ++r)
                            #pragma unroll
                            for (int c = 0; c < 4; ++c)
                                acc[i][r][c] += iv[r + ky][c + kx] * wv;
                    }
            }
        }
    }

    if (tid < 32) { redS[tid] = 0.f; redQ[tid] = 0.f; }
    __syncthreads();

    struct alignas(8) bf4 { __hip_bfloat16 v[4]; };
    #pragma unroll
    for (int i = 0; i < 4; ++i) {
        const int co = co_t * 32 + cog * 4 + i;
        const float bb = b2[co];
        float ls = 0.f, lq = 0.f;
        #pragma unroll
        for (int r = 0; r < 2; ++r) {
            bf4 pk;
            #pragma unroll
            for (int c = 0; c < 4; ++c) {
                float v = acc[i][r][c] + bb;
                ls += v; lq += v * v;
                pk.v[c] = __float2bfloat16(v);
            }
            *reinterpret_cast<bf4*>(&y2[((size_t)b * C1_ + co) * HW_ + (y0 + ry + r) * W_ + x0 + rx]) = pk;
        }
        atomicAdd(&redS[cog * 4 + i], ls);
        atomicAdd(&redQ[cog * 4 + i], lq);
    }
    __syncthreads();
    if (tid < 32) {
        atomicAdd(&sum2[co_t * 32 + tid], redS[tid]);
        atomicAdd(&sq2[co_t * 32 + tid], redQ[tid]);
    }
}

// ---------------- lateral path: maxpool2 + conv3x3(2->2) pad1 ----------------
__global__ __launch_bounds__(256) void poolconv_k(const float* __restrict__ out5,
                                                  const float* __restrict__ wl,
                                                  const float* __restrict__ bl,
                                                  float* __restrict__ ds) {
    int idx = blockIdx.x * 256 + threadIdx.x;   // 32*2*64*64
    int j = idx & 63;
    int i = (idx >> 6) & 63;
    int c = (idx >> 12) & 1;
    int b = idx >> 13;
    float acc = bl[c];
    #pragma unroll
    for (int ci = 0; ci < 2; ++ci) {
        const float* in = out5 + ((size_t)b * 5 + ci) * HW_;
        #pragma unroll
        for (int ky = 0; ky < 3; ++ky) {
            int ii = i + ky - 1;
            if (ii < 0 || ii > 63) continue;
            #pragma unroll
            for (int kx = 0; kx < 3; ++kx) {
                int jj = j + kx - 1;
                if (jj < 0 || jj > 63) continue;
                const float* p = in + (2 * ii) * W_ + 2 * jj;
                float pooled = fmaxf(fmaxf(p[0], p[1]), fmaxf(p[W_], p[W_ + 1]));
                acc += pooled * wl[(c * 2 + ci) * 9 + ky * 3 + kx];
            }
        }
    }
    ds[idx] = acc;
}

// ---------------- final: conv1x1(128->2 w/ BN2+ReLU on the fly) + upsample + softmax
//                  + elementwise sigmoid outputs ----------------
__global__ __launch_bounds__(256) void final_k(const float* __restrict__ out5,
                                               const __hip_bfloat16* __restrict__ y2,
                                               const float* __restrict__ s2,
                                               const float* __restrict__ t2,
                                               const float* __restrict__ w3,
                                               const float* __restrict__ b3,
                                               const float* __restrict__ dsb,
                                               float* __restrict__ out) {
    __shared__ float w3s[256], s2s[128], t2s[128];
    int tid = threadIdx.x;
    w3s[tid] = w3[tid];
    if (tid < 128) { s2s[tid] = s2[tid]; t2s[tid] = t2[tid]; }
    __syncthreads();
    int b = blockIdx.y;
    int y = blockIdx.x * 2 + (tid >> 7);
    int x = tid & 127;
    int p = y * W_ + x;

    const __hip_bfloat16* yp = y2 + (size_t)b * C1_ * HW_ + p;
    float jm0 = b3[0], jm1 = b3[1];
    for (int ci = 0; ci < 128; ++ci) {
        float h = fmaxf(s2s[ci] * __bfloat162float(yp[(size_t)ci * HW_]) + t2s[ci], 0.f);
        jm0 += h * w3s[ci];
        jm1 += h * w3s[128 + ci];
    }

    // bilinear upsample (align_corners) of ds [b][c][64][64]
    const float fo = (float)(63.0 / 127.0);
    float sy = (float)y * fo;
    int ly = (int)floorf(sy); ly = ly < 0 ? 0 : (ly > 62 ? 62 : ly);
    float wy = sy - (float)ly;
    float sx = (float)x * fo;
    int lx = (int)floorf(sx); lx = lx < 0 ? 0 : (lx > 62 ? 62 : lx);
    float wx = sx - (float)lx;
    float up[2];
    #pragma unroll
    for (int c = 0; c < 2; ++c) {
        const float* d = dsb + (((size_t)b * 2 + c) * 64) * 64;
        float d00 = d[ly * 64 + lx],       d01 = d[ly * 64 + lx + 1];
        float d10 = d[(ly + 1) * 64 + lx], d11 = d[(ly + 1) * 64 + lx + 1];
        up[c] = (1.f - wy) * ((1.f - wx) * d00 + wx * d01) + wy * ((1.f - wx) * d10 + wx * d11);
    }
    float dlt = (jm1 + up[1]) - (jm0 + up[0]);
    out[(size_t)b * HW_ + p] = 1.f / (1.f + expf(-dlt));                     // jmap_pred

    float lm = out5[((size_t)b * 5 + 2) * HW_ + p];
    out[524288 + (size_t)b * HW_ + p] = 1.f / (1.f + expf(-lm));             // lmap_pred

    float o3 = out5[((size_t)b * 5 + 3) * HW_ + p];
    float o4 = out5[((size_t)b * 5 + 4) * HW_ + p];
    out[1048576 + ((size_t)b * 2 + 0) * HW_ + p] = 1.f / (1.f + expf(-o3)) - 0.5f;  // joff
    out[1048576 + ((size_t)b * 2 + 1) * HW_ + p] = 1.f / (1.f + expf(-o4)) - 0.5f;
}

extern "C" void kernel_launch(void* const* d_in, const int* in_sizes, int n_in,
                              void* d_out, int out_size, void* d_ws, size_t ws_size,
                              hipStream_t stream) {
    const float* out5 = (const float*)d_in[0];
    const float* jmap = (const float*)d_in[1];
    const float* w1   = (const float*)d_in[2];
    const float* b1   = (const float*)d_in[3];
    const float* g1   = (const float*)d_in[4];
    const float* be1  = (const float*)d_in[5];
    const float* w2   = (const float*)d_in[6];
    const float* b2   = (const float*)d_in[7];
    const float* g2   = (const float*)d_in[8];
    const float* be2  = (const float*)d_in[9];
    const float* w3   = (const float*)d_in[10];
    const float* b3   = (const float*)d_in[11];
    const float* wl   = (const float*)d_in[12];
    const float* bl   = (const float*)d_in[13];
    const float* ga   = (const float*)d_in[14];
    const float* gb   = (const float*)d_in[15];
    float* out = (float*)d_out;

    // ws layout (total ~135.3 MB)
    char* ws = (char*)d_ws;
    __hip_bfloat16* y2 = (__hip_bfloat16*)ws;                // 134,217,728 B
    float* dsb = (float*)(ws + 134217728);                   // 1,048,576 B
    float* st  = (float*)(ws + 135266304);                   // 4 KB stats
    float* sum1 = st;        float* sq1 = st + 128;
    float* sum2 = st + 256;  float* sq2 = st + 384;
    float* s1 = st + 512;    float* t1 = st + 640;
    float* s2 = st + 768;    float* t2 = st + 896;

    float* gtmp = out + 2097152;   // gauss target region doubles as vertical-pass temp

    zero_k<<<1, 512, 0, stream>>>(st);
    gauss_v<<<dim3(64, 32), 256, 0, stream>>>(jmap, gtmp, ga, gb);
    gauss_h<<<dim3(64, 32), 256, 0, stream>>>(jmap, gtmp, ga, gb);
    conv1stats_k<<<dim3(16, 32), 256, 0, stream>>>(out5, w1, b1, sum1, sq1);
    bnp_k<<<1, 128, 0, stream>>>(sum1, sq1, g1, be1, s1, t1);
    conv2_k<<<dim3(16, 16, 32), 256, 0, stream>>>(out5, w1, b1, s1, t1, w2, b2, y2, sum2, sq2);
    bnp_k<<<1, 128, 0, stream>>>(sum2, sq2, g2, be2, s2, t2);
    poolconv_k<<<1024, 256, 0, stream>>>(out5, wl, bl, dsb);
    final_k<<<dim3(64, 32), 256, 0, stream>>>(out5, y2, s2, t2, w3, b3, dsb, out);
}

// Round 3
// 788.143 us; speedup vs baseline: 5.3199x; 5.3199x over previous
//
#include <hip/hip_runtime.h>
#include <hip/hip_bf16.h>

#define B_   32
#define H_   128
#define W_   128
#define HW_  16384
#define C1_  128

typedef __attribute__((ext_vector_type(8))) short short8;
typedef __attribute__((ext_vector_type(4))) float f32x4;

// ---------------- zero stats ----------------
__global__ void zero_k(float* p) { p[threadIdx.x] = 0.f; }

// ---------------- weight pre-transform: w2[co][ci][ky][kx] f32 -> w2t[cc][kk][co][40] bf16 ----
__global__ __launch_bounds__(256) void prep_w2t(const float* __restrict__ w2,
                                                unsigned short* __restrict__ w2t) {
    int idx = blockIdx.x * 256 + threadIdx.x;   // 4*9*128*40 = 184320
    if (idx >= 184320) return;
    int slot = idx % 40;
    int t = idx / 40;
    int co = t % 128; t /= 128;
    int kk = t % 9;  int cc = t / 9;
    unsigned short v = 0;
    if (slot < 32) {
        float f = w2[((size_t)co * 128 + (cc * 32 + slot)) * 9 + kk];
        __hip_bfloat16 bb = __float2bfloat16(f);
        v = *reinterpret_cast<unsigned short*>(&bb);
    }
    w2t[idx] = v;
}

// ---------------- gaussian splat: vertical pass ----------------
__global__ __launch_bounds__(256) void gauss_v(const float* __restrict__ jmap,
                                               float* __restrict__ gtmp,
                                               const float* __restrict__ ga,
                                               const float* __restrict__ gb) {
    __shared__ float k1[255];
    float a = ga[0] / (gb[0] * gb[0]);
    for (int i = threadIdx.x; i < 255; i += 256) {
        float d = (float)(i - 127);
        k1[i] = expf(a * d * d);
    }
    __syncthreads();
    int b = blockIdx.y;
    int y = blockIdx.x * 2 + (threadIdx.x >> 7);
    int x = threadIdx.x & 127;
    const float* m = jmap + (size_t)b * HW_;
    float s = 0.f;
    for (int yy = 0; yy < H_; ++yy) {
        float mv = m[yy * W_ + x];
        s += (mv == 1.0f) ? k1[yy - y + 127] : 0.f;
    }
    gtmp[(size_t)b * HW_ + y * W_ + x] = s;
}

// ---------------- gaussian splat: horizontal pass + finalize (in-place) ----------------
__global__ __launch_bounds__(256) void gauss_h(const float* __restrict__ jmap,
                                               float* __restrict__ gtmp,
                                               const float* __restrict__ ga,
                                               const float* __restrict__ gb) {
    __shared__ float k1[255];
    __shared__ float row[256];
    float a = ga[0] / (gb[0] * gb[0]);
    for (int i = threadIdx.x; i < 255; i += 256) {
        float d = (float)(i - 127);
        k1[i] = expf(a * d * d);
    }
    int b = blockIdx.y;
    int y0 = blockIdx.x * 2;
    int tid = threadIdx.x;
    row[tid] = gtmp[(size_t)b * HW_ + (y0 + (tid >> 7)) * W_ + (tid & 127)];
    __syncthreads();
    int y = y0 + (tid >> 7);
    int x = tid & 127;
    int base = (tid >> 7) * 128;
    float s = 0.f;
    for (int xx = 0; xx < W_; ++xx)
        s += k1[xx - x + 127] * row[base + xx];
    float g = jmap[(size_t)b * HW_ + y * W_ + x] + s;
    g = (g <= 0.05f) ? 0.f : fminf(g, 1.0f);
    gtmp[(size_t)b * HW_ + y * W_ + x] = g;
}

// ---------------- conv1 stats only ----------------
__global__ __launch_bounds__(256) void conv1stats_k(const float* __restrict__ out5,
                                                    const float* __restrict__ w1,
                                                    const float* __restrict__ b1,
                                                    float* __restrict__ sum1,
                                                    float* __restrict__ sq1) {
    int cg = blockIdx.x;
    int b  = blockIdx.y;
    int tid = threadIdx.x;
    __shared__ float wsh[8][18];
    __shared__ float bsh[8];
    __shared__ float red[256];
    for (int i = tid; i < 144; i += 256) wsh[i / 18][i % 18] = w1[cg * 8 * 18 + i];
    if (tid < 8) bsh[tid] = b1[cg * 8 + tid];
    __syncthreads();
    float ls[8], lq[8];
    #pragma unroll
    for (int i = 0; i < 8; ++i) { ls[i] = 0.f; lq[i] = 0.f; }
    const float* in0 = out5 + (size_t)b * 5 * HW_;
    const float* in1 = in0 + HW_;
    for (int pos = tid; pos < HW_; pos += 256) {
        int y = pos >> 7, x = pos & 127;
        float v0[9], v1[9];
        #pragma unroll
        for (int ky = 0; ky < 3; ++ky)
            #pragma unroll
            for (int kx = 0; kx < 3; ++kx) {
                int yy = y + ky - 1, xx = x + kx - 1;
                bool ok = ((unsigned)yy < 128u) && ((unsigned)xx < 128u);
                v0[ky * 3 + kx] = ok ? in0[yy * W_ + xx] : 0.f;
                v1[ky * 3 + kx] = ok ? in1[yy * W_ + xx] : 0.f;
            }
        #pragma unroll
        for (int i = 0; i < 8; ++i) {
            float a = bsh[i];
            #pragma unroll
            for (int k = 0; k < 9; ++k) a += v0[k] * wsh[i][k] + v1[k] * wsh[i][9 + k];
            ls[i] += a; lq[i] += a * a;
        }
    }
    for (int i = 0; i < 8; ++i) {
        red[tid] = ls[i]; __syncthreads();
        for (int s = 128; s > 0; s >>= 1) { if (tid < s) red[tid] += red[tid + s]; __syncthreads(); }
        if (tid == 0) atomicAdd(&sum1[cg * 8 + i], red[0]);
        __syncthreads();
        red[tid] = lq[i]; __syncthreads();
        for (int s = 128; s > 0; s >>= 1) { if (tid < s) red[tid] += red[tid + s]; __syncthreads(); }
        if (tid == 0) atomicAdd(&sq1[cg * 8 + i], red[0]);
        __syncthreads();
    }
}

// ---------------- BN params ----------------
__global__ void bnp_k(const float* __restrict__ sum, const float* __restrict__ sq,
                      const float* __restrict__ gamma, const float* __restrict__ beta,
                      float* __restrict__ s, float* __restrict__ t) {
    int c = threadIdx.x;
    const float N = (float)(B_ * HW_);
    float m = sum[c] / N;
    float v = sq[c] / N - m * m;
    float sc = gamma[c] / sqrtf(v + 1e-5f);
    s[c] = sc;
    t[c] = beta[c] - sc * m;
}

// ---------------- conv2 via MFMA: recompute conv1+BN1+ReLU into LDS, implicit GEMM ----
// block 512 thr (8 waves), tile: co 128 x pos 256 (2 rows). K=1152 in 4 ci-chunks x 9 taps.
__global__ __launch_bounds__(512) void conv2_mfma(const float* __restrict__ out5,
                                                  const float* __restrict__ w1,
                                                  const float* __restrict__ b1,
                                                  const float* __restrict__ s1,
                                                  const float* __restrict__ t1,
                                                  const unsigned short* __restrict__ w2t,
                                                  const float* __restrict__ b2,
                                                  __hip_bfloat16* __restrict__ y2,
                                                  float* __restrict__ sum2,
                                                  float* __restrict__ sq2) {
    __shared__ unsigned short inT[4 * 130 * 40];   // 41600 B, h1 bf16, pad-40 stride
    __shared__ unsigned short wT[128 * 40];        // 10240 B
    __shared__ float redS[128], redQ[128];

    const int tid = threadIdx.x;
    const int b  = blockIdx.x >> 6;
    const int yp = blockIdx.x & 63;
    const int y0 = yp * 2;

    if (tid < 128) { redS[tid] = 0.f; redQ[tid] = 0.f; }

    const int lane = tid & 63;
    const int w = tid >> 6;
    const int wm = w & 1, wn = w >> 1;
    const int l15 = lane & 15, kg = lane >> 4;

    f32x4 acc[4][4];
    #pragma unroll
    for (int fm = 0; fm < 4; ++fm)
        #pragma unroll
        for (int fn = 0; fn < 4; ++fn) acc[fm][fn] = (f32x4){0.f, 0.f, 0.f, 0.f};

    // staging assignment: (staged row sr, ci-in-chunk sci) x 4 pos-segments
    const int pair = tid >> 2;       // 0..127
    const int sr  = pair >> 5;       // 0..3
    const int sci = pair & 31;       // 0..31
    const int sub = tid & 3;
    const int p_begin = sub * 33;
    const int p_end = (p_begin + 33 < 130) ? (p_begin + 33) : 130;
    const int gy = y0 + sr - 1;
    const bool rowok = (unsigned)gy < 128u;

    const float* base0 = out5 + (size_t)b * 5 * HW_;
    const float* base1 = base0 + HW_;

    for (int cc = 0; cc < 4; ++cc) {
        __syncthreads();   // prior iter's MFMA done reading inT
        // ---- stage inT: conv1+BN1+ReLU for ci chunk cc ----
        {
            const int cig = cc * 32 + sci;
            float wr[18];
            #pragma unroll
            for (int k = 0; k < 18; ++k) wr[k] = w1[cig * 18 + k];
            const float sc = s1[cig];
            const float tp = fmaf(sc, b1[cig], t1[cig]);   // fold conv1 bias into BN shift
            if (!rowok) {
                for (int p = p_begin; p < p_end; ++p)
                    inT[(sr * 130 + p) * 40 + sci] = 0;
            } else {
                const bool okm = (unsigned)(gy - 1) < 128u;
                const bool okp2 = (unsigned)(gy + 1) < 128u;
                const int rm = (gy - 1) * W_, rz = gy * W_, rp = (gy + 1) * W_;
                // prime cols gx = p_begin-2, p_begin-1
                float c0a, c0b, c0c, c1a, c1b, c1c;   // left col
                float d0a, d0b, d0c, d1a, d1b, d1c;   // mid col
                {
                    int g = p_begin - 2;
                    bool ok = (unsigned)g < 128u;
                    c0a = (ok && okm)  ? base0[rm + g] : 0.f;
                    c0b = ok           ? base0[rz + g] : 0.f;
                    c0c = (ok && okp2) ? base0[rp + g] : 0.f;
                    c1a = (ok && okm)  ? base1[rm + g] : 0.f;
                    c1b = ok           ? base1[rz + g] : 0.f;
                    c1c = (ok && okp2) ? base1[rp + g] : 0.f;
                    g = p_begin - 1;
                    ok = (unsigned)g < 128u;
                    d0a = (ok && okm)  ? base0[rm + g] : 0.f;
                    d0b = ok           ? base0[rz + g] : 0.f;
                    d0c = (ok && okp2) ? base0[rp + g] : 0.f;
                    d1a = (ok && okm)  ? base1[rm + g] : 0.f;
                    d1b = ok           ? base1[rz + g] : 0.f;
                    d1c = (ok && okp2) ? base1[rp + g] : 0.f;
                }
                for (int p = p_begin; p < p_end; ++p) {
                    int g = p;   // new right col
                    bool ok = (unsigned)g < 128u;
                    float e0a = (ok && okm)  ? base0[rm + g] : 0.f;
                    float e0b = ok           ? base0[rz + g] : 0.f;
                    float e0c = (ok && okp2) ? base0[rp + g] : 0.f;
                    float e1a = (ok && okm)  ? base1[rm + g] : 0.f;
                    float e1b = ok           ? base1[rz + g] : 0.f;
                    float e1c = (ok && okp2) ? base1[rp + g] : 0.f;
                    unsigned short hv = 0;
                    if ((unsigned)(p - 1) < 128u) {
                        float a = c0a * wr[0]  + d0a * wr[1]  + e0a * wr[2]
                                + c0b * wr[3]  + d0b * wr[4]  + e0b * wr[5]
                                + c0c * wr[6]  + d0c * wr[7]  + e0c * wr[8]
                                + c1a * wr[9]  + d1a * wr[10] + e1a * wr[11]
                                + c1b * wr[12] + d1b * wr[13] + e1b * wr[14]
                                + c1c * wr[15] + d1c * wr[16] + e1c * wr[17];
                        float h = fmaxf(fmaf(sc, a, tp), 0.f);
                        __hip_bfloat16 hb = __float2bfloat16(h);
                        hv = *reinterpret_cast<unsigned short*>(&hb);
                    }
                    inT[(sr * 130 + p) * 40 + sci] = hv;
                    c0a = d0a; c0b = d0b; c0c = d0c; d0a = e0a; d0b = e0b; d0c = e0c;
                    c1a = d1a; c1b = d1b; c1c = d1c; d1a = e1a; d1b = e1b; d1c = e1c;
                }
            }
        }

        const unsigned short* wsrc_cc = w2t + (size_t)cc * 9 * 5120;
        #pragma unroll
        for (int kk = 0; kk < 9; ++kk) {
            const int ky = kk / 3, kx = kk % 3;
            __syncthreads();   // kk==0: inT writes visible; kk>0: prev wT reads done
            {
                const short8* src = (const short8*)(wsrc_cc + kk * 5120);
                short8* dst = (short8*)wT;
                dst[tid] = src[tid];
                if (tid < 128) dst[512 + tid] = src[512 + tid];
            }
            __syncthreads();   // wT ready
            short8 af[4];
            #pragma unroll
            for (int fm = 0; fm < 4; ++fm) {
                int co_l = wm * 64 + fm * 16 + l15;
                af[fm] = *(const short8*)&wT[co_l * 40 + kg * 8];
            }
            short8 bf[4];
            #pragma unroll
            for (int fn = 0; fn < 4; ++fn) {
                int n = wn * 64 + fn * 16 + l15;
                int r = (n >> 7) + ky;
                int p = (n & 127) + kx;
                bf[fn] = *(const short8*)&inT[(r * 130 + p) * 40 + kg * 8];
            }
            #pragma unroll
            for (int fm = 0; fm < 4; ++fm)
                #pragma unroll
                for (int fn = 0; fn < 4; ++fn)
                    acc[fm][fn] = __builtin_amdgcn_mfma_f32_16x16x32_bf16(af[fm], bf[fn], acc[fm][fn], 0, 0, 0);
        }
    }

    // ---- epilogue: bias, store bf16, stats ----
    #pragma unroll
    for (int fm = 0; fm < 4; ++fm) {
        #pragma unroll
        for (int r = 0; r < 4; ++r) {
            const int co = wm * 64 + fm * 16 + kg * 4 + r;
            const float bb = b2[co];
            float ls = 0.f, lq = 0.f;
            #pragma unroll
            for (int fn = 0; fn < 4; ++fn) {
                float v = acc[fm][fn][r] + bb;
                ls += v; lq += v * v;
                int n = wn * 64 + fn * 16 + l15;
                y2[(((size_t)b * C1_ + co) * H_ + (y0 + (n >> 7))) * W_ + (n & 127)] = __float2bfloat16(v);
            }
            #pragma unroll
            for (int m = 1; m < 16; m <<= 1) {
                ls += __shfl_xor(ls, m, 64);
                lq += __shfl_xor(lq, m, 64);
            }
            if (l15 == 0) { atomicAdd(&redS[co], ls); atomicAdd(&redQ[co], lq); }
        }
    }
    __syncthreads();
    if (tid < 128) { atomicAdd(&sum2[tid], redS[tid]); atomicAdd(&sq2[tid], redQ[tid]); }
}

// ---------------- lateral path: maxpool2 + conv3x3(2->2) pad1 ----------------
__global__ __launch_bounds__(256) void poolconv_k(const float* __restrict__ out5,
                                                  const float* __restrict__ wl,
                                                  const float* __restrict__ bl,
                                                  float* __restrict__ ds) {
    int idx = blockIdx.x * 256 + threadIdx.x;
    int j = idx & 63;
    int i = (idx >> 6) & 63;
    int c = (idx >> 12) & 1;
    int b = idx >> 13;
    float acc = bl[c];
    #pragma unroll
    for (int ci = 0; ci < 2; ++ci) {
        const float* in = out5 + ((size_t)b * 5 + ci) * HW_;
        #pragma unroll
        for (int ky = 0; ky < 3; ++ky) {
            int ii = i + ky - 1;
            if (ii < 0 || ii > 63) continue;
            #pragma unroll
            for (int kx = 0; kx < 3; ++kx) {
                int jj = j + kx - 1;
                if (jj < 0 || jj > 63) continue;
                const float* p = in + (2 * ii) * W_ + 2 * jj;
                float pooled = fmaxf(fmaxf(p[0], p[1]), fmaxf(p[W_], p[W_ + 1]));
                acc += pooled * wl[(c * 2 + ci) * 9 + ky * 3 + kx];
            }
        }
    }
    ds[idx] = acc;
}

// ---------------- final: conv1x1(BN2+ReLU) + upsample + softmax + sigmoids, 8 px/thread ----
__global__ __launch_bounds__(256) void final_k(const float* __restrict__ out5,
                                               const __hip_bfloat16* __restrict__ y2,
                                               const float* __restrict__ s2,
                                               const float* __restrict__ t2,
                                               const float* __restrict__ w3,
                                               const float* __restrict__ b3,
                                               const float* __restrict__ dsb,
                                               float* __restrict__ out) {
    __shared__ float w3s[256], s2s[128], t2s[128];
    int tid = threadIdx.x;
    w3s[tid] = w3[tid];
    if (tid < 128) { s2s[tid] = s2[tid]; t2s[tid] = t2[tid]; }
    __syncthreads();
    int gid = blockIdx.x * 256 + tid;          // 65536
    int b = gid >> 11;
    int rem = gid & 2047;
    int y = rem >> 4;
    int x0 = (rem & 15) * 8;
    int p = y * W_ + x0;

    const unsigned short* yp = (const unsigned short*)y2 + (size_t)b * C1_ * HW_ + p;
    float jm0[8], jm1[8];
    #pragma unroll
    for (int i = 0; i < 8; ++i) { jm0[i] = b3[0]; jm1[i] = b3[1]; }
    for (int ci = 0; ci < 128; ++ci) {
        short8 v = *(const short8*)(yp + (size_t)ci * HW_);
        float sc = s2s[ci], tc = t2s[ci];
        float w0 = w3s[ci], w1c = w3s[128 + ci];
        #pragma unroll
        for (int i = 0; i < 8; ++i) {
            union { unsigned int ui; float f; } cv;
            cv.ui = ((unsigned)(unsigned short)v[i]) << 16;
            float h = fmaxf(fmaf(sc, cv.f, tc), 0.f);
            jm0[i] = fmaf(h, w0, jm0[i]);
            jm1[i] = fmaf(h, w1c, jm1[i]);
        }
    }

    const float fo = (float)(63.0 / 127.0);
    float sy = (float)y * fo;
    int ly = (int)floorf(sy); ly = ly < 0 ? 0 : (ly > 62 ? 62 : ly);
    float wy = sy - (float)ly;
    const float* dbase = dsb + ((size_t)b * 2) * 4096;
    #pragma unroll
    for (int i = 0; i < 8; ++i) {
        int x = x0 + i;
        float sx = (float)x * fo;
        int lx = (int)floorf(sx); lx = lx < 0 ? 0 : (lx > 62 ? 62 : lx);
        float wx = sx - (float)lx;
        float up[2];
        #pragma unroll
        for (int c = 0; c < 2; ++c) {
            const float* d = dbase + c * 4096;
            float d00 = d[ly * 64 + lx],       d01 = d[ly * 64 + lx + 1];
            float d10 = d[(ly + 1) * 64 + lx], d11 = d[(ly + 1) * 64 + lx + 1];
            up[c] = (1.f - wy) * ((1.f - wx) * d00 + wx * d01) + wy * ((1.f - wx) * d10 + wx * d11);
        }
        float dlt = (jm1[i] + up[1]) - (jm0[i] + up[0]);
        out[(size_t)b * HW_ + p + i] = 1.f / (1.f + expf(-dlt));
    }
    #pragma unroll
    for (int i = 0; i < 8; ++i) {
        float lm = out5[((size_t)b * 5 + 2) * HW_ + p + i];
        out[524288 + (size_t)b * HW_ + p + i] = 1.f / (1.f + expf(-lm));
    }
    #pragma unroll
    for (int i = 0; i < 8; ++i) {
        float o3 = out5[((size_t)b * 5 + 3) * HW_ + p + i];
        float o4 = out5[((size_t)b * 5 + 4) * HW_ + p + i];
        out[1048576 + ((size_t)b * 2 + 0) * HW_ + p + i] = 1.f / (1.f + expf(-o3)) - 0.5f;
        out[1048576 + ((size_t)b * 2 + 1) * HW_ + p + i] = 1.f / (1.f + expf(-o4)) - 0.5f;
    }
}

extern "C" void kernel_launch(void* const* d_in, const int* in_sizes, int n_in,
                              void* d_out, int out_size, void* d_ws, size_t ws_size,
                              hipStream_t stream) {
    const float* out5 = (const float*)d_in[0];
    const float* jmap = (const float*)d_in[1];
    const float* w1   = (const float*)d_in[2];
    const float* b1   = (const float*)d_in[3];
    const float* g1   = (const float*)d_in[4];
    const float* be1  = (const float*)d_in[5];
    const float* w2   = (const float*)d_in[6];
    const float* b2   = (const float*)d_in[7];
    const float* g2   = (const float*)d_in[8];
    const float* be2  = (const float*)d_in[9];
    const float* w3   = (const float*)d_in[10];
    const float* b3   = (const float*)d_in[11];
    const float* wl   = (const float*)d_in[12];
    const float* bl   = (const float*)d_in[13];
    const float* ga   = (const float*)d_in[14];
    const float* gb   = (const float*)d_in[15];
    float* out = (float*)d_out;

    // ws layout (total 135,270,400 B — same as round 2):
    //   [0, 134217728)           y2 bf16
    //   [134217728, +1048576)    shared region: w2t (368640 B, used by conv2) then dsb (pool output)
    //   [135266304, +4096)       stats
    char* ws = (char*)d_ws;
    __hip_bfloat16* y2 = (__hip_bfloat16*)ws;
    unsigned short* w2t = (unsigned short*)(ws + 134217728);
    float* dsb = (float*)(ws + 134217728);
    float* st  = (float*)(ws + 135266304);
    float* sum1 = st;        float* sq1 = st + 128;
    float* sum2 = st + 256;  float* sq2 = st + 384;
    float* s1 = st + 512;    float* t1 = st + 640;
    float* s2 = st + 768;    float* t2 = st + 896;

    float* gtmp = out + 2097152;   // gauss region doubles as vertical-pass temp

    zero_k<<<1, 512, 0, stream>>>(st);
    prep_w2t<<<720, 256, 0, stream>>>(w2, w2t);
    gauss_v<<<dim3(64, 32), 256, 0, stream>>>(jmap, gtmp, ga, gb);
    gauss_h<<<dim3(64, 32), 256, 0, stream>>>(jmap, gtmp, ga, gb);
    conv1stats_k<<<dim3(16, 32), 256, 0, stream>>>(out5, w1, b1, sum1, sq1);
    bnp_k<<<1, 128, 0, stream>>>(sum1, sq1, g1, be1, s1, t1);
    conv2_mfma<<<2048, 512, 0, stream>>>(out5, w1, b1, s1, t1, w2t, b2, y2, sum2, sq2);
    bnp_k<<<1, 128, 0, stream>>>(sum2, sq2, g2, be2, s2, t2);
    poolconv_k<<<1024, 256, 0, stream>>>(out5, wl, bl, dsb);
    final_k<<<256, 256, 0, stream>>>(out5, y2, s2, t2, w3, b3, dsb, out);
}

// Round 5
// 436.695 us; speedup vs baseline: 9.6012x; 1.8048x over previous
//
#include <hip/hip_runtime.h>
#include <hip/hip_bf16.h>

#define B_   32
#define H_   128
#define W_   128
#define HW_  16384
#define C1_  128

typedef __attribute__((ext_vector_type(8))) short short8;
typedef __attribute__((ext_vector_type(4))) short short4v;
typedef __attribute__((ext_vector_type(4))) float f32x4;

static __device__ __forceinline__ unsigned short bfbits(float f) {
    __hip_bfloat16 h = __float2bfloat16(f);
    return *reinterpret_cast<unsigned short*>(&h);
}

// ---------------- zero stats ----------------
__global__ void zero_k(float* p) { p[threadIdx.x] = 0.f; }

// ---- weight prep: w2[co][ci][kk] f32 -> w2t2[cc][kk][kg][co][8] bf16 (147456 shorts) ----
__global__ __launch_bounds__(256) void prep_w2t2(const float* __restrict__ w2,
                                                 unsigned short* __restrict__ w2t2) {
    int idx = blockIdx.x * 256 + threadIdx.x;
    if (idx >= 147456) return;
    int e  = idx & 7;
    int co = (idx >> 3) & 127;
    int kg = (idx >> 10) & 3;
    int t  = idx >> 12;          // 0..35
    int kk = t % 9, cc = t / 9;
    int ci = cc * 32 + kg * 8 + e;
    w2t2[idx] = bfbits(w2[((size_t)co * 128 + ci) * 9 + kk]);
}

// ---- weight prep: w1[ci][18] f32 -> w1t[ci][32] bf16, zero-padded K 18..31 ----
__global__ __launch_bounds__(256) void prep_w1t(const float* __restrict__ w1,
                                                unsigned short* __restrict__ w1t) {
    int idx = blockIdx.x * 256 + threadIdx.x;
    if (idx >= 4096) return;
    int k = idx & 31, ci = idx >> 5;
    w1t[idx] = (k < 18) ? bfbits(w1[ci * 18 + k]) : (unsigned short)0;
}

// ---------------- gaussian splat: vertical pass ----------------
__global__ __launch_bounds__(256) void gauss_v(const float* __restrict__ jmap,
                                               float* __restrict__ gtmp,
                                               const float* __restrict__ ga,
                                               const float* __restrict__ gb) {
    __shared__ float k1[255];
    float a = ga[0] / (gb[0] * gb[0]);
    for (int i = threadIdx.x; i < 255; i += 256) {
        float d = (float)(i - 127);
        k1[i] = expf(a * d * d);
    }
    __syncthreads();
    int b = blockIdx.y;
    int y = blockIdx.x * 2 + (threadIdx.x >> 7);
    int x = threadIdx.x & 127;
    const float* m = jmap + (size_t)b * HW_;
    float s = 0.f;
    for (int yy = 0; yy < H_; ++yy) {
        float mv = m[yy * W_ + x];
        s += (mv == 1.0f) ? k1[yy - y + 127] : 0.f;
    }
    gtmp[(size_t)b * HW_ + y * W_ + x] = s;
}

// ---------------- gaussian splat: horizontal pass + finalize (in-place) ----------------
__global__ __launch_bounds__(256) void gauss_h(const float* __restrict__ jmap,
                                               float* __restrict__ gtmp,
                                               const float* __restrict__ ga,
                                               const float* __restrict__ gb) {
    __shared__ float k1[255];
    __shared__ float row[256];
    float a = ga[0] / (gb[0] * gb[0]);
    for (int i = threadIdx.x; i < 255; i += 256) {
        float d = (float)(i - 127);
        k1[i] = expf(a * d * d);
    }
    int b = blockIdx.y;
    int y0 = blockIdx.x * 2;
    int tid = threadIdx.x;
    row[tid] = gtmp[(size_t)b * HW_ + (y0 + (tid >> 7)) * W_ + (tid & 127)];
    __syncthreads();
    int y = y0 + (tid >> 7);
    int x = tid & 127;
    int base = (tid >> 7) * 128;
    float s = 0.f;
    for (int xx = 0; xx < W_; ++xx)
        s += k1[xx - x + 127] * row[base + xx];
    float g = jmap[(size_t)b * HW_ + y * W_ + x] + s;
    g = (g <= 0.05f) ? 0.f : fminf(g, 1.0f);
    gtmp[(size_t)b * HW_ + y * W_ + x] = g;
}

// ---------------- conv1 stats only (exact f32) ----------------
__global__ __launch_bounds__(256) void conv1stats_k(const float* __restrict__ out5,
                                                    const float* __restrict__ w1,
                                                    const float* __restrict__ b1,
                                                    float* __restrict__ sum1,
                                                    float* __restrict__ sq1) {
    int cg = blockIdx.x;
    int b  = blockIdx.y;
    int tid = threadIdx.x;
    __shared__ float wsh[8][18];
    __shared__ float bsh[8];
    __shared__ float red[256];
    for (int i = tid; i < 144; i += 256) wsh[i / 18][i % 18] = w1[cg * 8 * 18 + i];
    if (tid < 8) bsh[tid] = b1[cg * 8 + tid];
    __syncthreads();
    float ls[8], lq[8];
    #pragma unroll
    for (int i = 0; i < 8; ++i) { ls[i] = 0.f; lq[i] = 0.f; }
    const float* in0 = out5 + (size_t)b * 5 * HW_;
    const float* in1 = in0 + HW_;
    for (int pos = tid; pos < HW_; pos += 256) {
        int y = pos >> 7, x = pos & 127;
        float v0[9], v1[9];
        #pragma unroll
        for (int ky = 0; ky < 3; ++ky)
            #pragma unroll
            for (int kx = 0; kx < 3; ++kx) {
                int yy = y + ky - 1, xx = x + kx - 1;
                bool ok = ((unsigned)yy < 128u) && ((unsigned)xx < 128u);
                v0[ky * 3 + kx] = ok ? in0[yy * W_ + xx] : 0.f;
                v1[ky * 3 + kx] = ok ? in1[yy * W_ + xx] : 0.f;
            }
        #pragma unroll
        for (int i = 0; i < 8; ++i) {
            float a = bsh[i];
            #pragma unroll
            for (int k = 0; k < 9; ++k) a += v0[k] * wsh[i][k] + v1[k] * wsh[i][9 + k];
            ls[i] += a; lq[i] += a * a;
        }
    }
    for (int i = 0; i < 8; ++i) {
        red[tid] = ls[i]; __syncthreads();
        for (int s = 128; s > 0; s >>= 1) { if (tid < s) red[tid] += red[tid + s]; __syncthreads(); }
        if (tid == 0) atomicAdd(&sum1[cg * 8 + i], red[0]);
        __syncthreads();
        red[tid] = lq[i]; __syncthreads();
        for (int s = 128; s > 0; s >>= 1) { if (tid < s) red[tid] += red[tid + s]; __syncthreads(); }
        if (tid == 0) atomicAdd(&sq1[cg * 8 + i], red[0]);
        __syncthreads();
    }
}

// ---------------- BN params ----------------
__global__ void bnp_k(const float* __restrict__ sum, const float* __restrict__ sq,
                      const float* __restrict__ gamma, const float* __restrict__ beta,
                      float* __restrict__ s, float* __restrict__ t) {
    int c = threadIdx.x;
    const float N = (float)(B_ * HW_);
    float m = sum[c] / N;
    float v = sq[c] / N - m * m;
    float sc = gamma[c] / sqrtf(v + 1e-5f);
    s[c] = sc;
    t[c] = beta[c] - sc * m;
}

// ---------------- conv2 via MFMA, conv1 ALSO via MFMA (im2col in LDS) ----------------
// block 512 thr (8 waves), out tile: co 128 x pos 256 (2 rows). 4 ci-chunks x 9 taps.
// ib K-stride = 32 with slots 18..31 and rows 520..527 explicitly ZEROED so every
// B-fragment read (incl. kg=3 and ghost columns q>=520) hits written zeros.
__global__ __launch_bounds__(512, 2) void conv2_mfma(
    const float* __restrict__ out5,
    const float* __restrict__ b1,
    const float* __restrict__ s1,
    const float* __restrict__ t1,
    const unsigned short* __restrict__ w2t2,
    const unsigned short* __restrict__ w1t,
    const float* __restrict__ b2,
    __hip_bfloat16* __restrict__ y2,
    float* __restrict__ sum2,
    float* __restrict__ sq2)
{
    __shared__ unsigned short ib[528 * 32];      // 33792 B  im2col (K=18 pad 32, zeroed)
    __shared__ unsigned short inT[4 * 130 * 40]; // 41600 B  h1 chunk (32 ci, pad 40)
    __shared__ unsigned short wc[20480];         // 40960 B  conv2 weights, <=5 taps
    __shared__ float s1sh[128], t1sh[128], redS[128], redQ[128];

    const int tid = threadIdx.x;
    const int b  = blockIdx.x >> 6;
    const int y0 = (blockIdx.x & 63) * 2;
    const int lane = tid & 63, w = tid >> 6;
    const int wm = w & 1, wn = w >> 1;
    const int l15 = lane & 15, kg = lane >> 4;

    if (tid < 128) {
        redS[tid] = 0.f; redQ[tid] = 0.f;
        float sv = s1[tid];
        s1sh[tid] = sv;
        t1sh[tid] = fmaf(sv, b1[tid], t1[tid]);   // fold conv1 bias into BN shift
    }

    // conv1 weight fragments (registers, K padded to 32 with zeros)
    short8 a1[4][2];
    #pragma unroll
    for (int cc = 0; cc < 4; ++cc)
        #pragma unroll
        for (int mi = 0; mi < 2; ++mi)
            a1[cc][mi] = *(const short8*)&w1t[(cc * 32 + mi * 16 + l15) * 32 + kg * 8];

    // ---- build im2col ib once (fully initialized: pads + ghost rows zeroed) ----
    const float* in0 = out5 + (size_t)b * 5 * HW_;
    const float* in1 = in0 + HW_;
    for (int q = tid; q < 528; q += 512) {
        short8 p0 = (short8){0,0,0,0,0,0,0,0};
        short8 p1 = p0, p2 = p0, p3 = p0;
        if (q < 520) {
            int r = q / 130, c = q - r * 130;
            int gy = y0 - 1 + r, gx = c - 1;
            unsigned short vals[18];
            #pragma unroll
            for (int ch = 0; ch < 2; ++ch) {
                const float* src = ch ? in1 : in0;
                #pragma unroll
                for (int ky = 0; ky < 3; ++ky) {
                    int yy = gy + ky - 1;
                    bool yok = (unsigned)yy < 128u;
                    #pragma unroll
                    for (int kx = 0; kx < 3; ++kx) {
                        int xx = gx + kx - 1;
                        float v = (yok && (unsigned)xx < 128u) ? src[yy * W_ + xx] : 0.f;
                        vals[ch * 9 + ky * 3 + kx] = bfbits(v);
                    }
                }
            }
            #pragma unroll
            for (int j = 0; j < 8; ++j) { p0[j] = vals[j]; p1[j] = vals[8 + j]; }
            p2[0] = vals[16]; p2[1] = vals[17];
        }
        *(short8*)&ib[q * 32]      = p0;
        *(short8*)&ib[q * 32 + 8]  = p1;
        *(short8*)&ib[q * 32 + 16] = p2;
        *(short8*)&ib[q * 32 + 24] = p3;
    }
    __syncthreads();

    f32x4 acc[4][4];
    #pragma unroll
    for (int fm = 0; fm < 4; ++fm)
        #pragma unroll
        for (int fn = 0; fn < 4; ++fn) acc[fm][fn] = (f32x4){0.f, 0.f, 0.f, 0.f};

    for (int cc = 0; cc < 4; ++cc) {
        const unsigned short* wsrc = w2t2 + cc * 36864;
        // issue taps 0-4 weight loads (consumed after h1 phase -> latency hidden)
        short8 stA[5];
        #pragma unroll
        for (int u = 0; u < 5; ++u) stA[u] = *(const short8*)&wsrc[(u * 512 + tid) * 8];

        // ---- h1 chunk via MFMA: 66 tiles (2 mi x 33 nj) over 8 waves ----
        for (int t = w; t < 66; t += 8) {
            int mi = t & 1, nj = t >> 1;
            int q = nj * 16 + l15;
            short8 bfb = *(const short8*)&ib[q * 32 + kg * 8];
            f32x4 hacc = (f32x4){0.f, 0.f, 0.f, 0.f};
            hacc = __builtin_amdgcn_mfma_f32_16x16x32_bf16(a1[cc][mi], bfb, hacc, 0, 0, 0);
            int r = q / 130, c = q - r * 130;
            int gy = y0 - 1 + r;
            bool zero = (q >= 520) || ((unsigned)gy >= 128u) || (c == 0) || (c == 129);
            short4v hv;
            #pragma unroll
            for (int rr = 0; rr < 4; ++rr) {
                int cig = cc * 32 + mi * 16 + kg * 4 + rr;
                float h = fmaxf(fmaf(s1sh[cig], hacc[rr], t1sh[cig]), 0.f);
                hv[rr] = zero ? (short)0 : (short)bfbits(h);
            }
            if (q < 520)
                *(short4v*)&inT[(r * 130 + c) * 40 + mi * 16 + kg * 4] = hv;
        }
        #pragma unroll
        for (int u = 0; u < 5; ++u) *(short8*)&wc[(u * 512 + tid) * 8] = stA[u];
        __syncthreads();   // inT + wc(taps0-4) ready

        // issue taps 5-8 loads (hidden under taps0-4 MFMA)
        short8 stB[4];
        #pragma unroll
        for (int u = 0; u < 4; ++u) stB[u] = *(const short8*)&wsrc[20480 + (u * 512 + tid) * 8];

        #pragma unroll
        for (int kk = 0; kk < 5; ++kk) {
            const int ky = kk / 3, kx = kk % 3;
            short8 af[4], bfv[4];
            #pragma unroll
            for (int fm = 0; fm < 4; ++fm)
                af[fm] = *(const short8*)&wc[((kk * 4 + kg) * 128 + wm * 64 + fm * 16 + l15) * 8];
            #pragma unroll
            for (int fn = 0; fn < 4; ++fn) {
                int n = wn * 64 + fn * 16 + l15;
                int r = (n >> 7) + ky, c = (n & 127) + kx;
                bfv[fn] = *(const short8*)&inT[(r * 130 + c) * 40 + kg * 8];
            }
            #pragma unroll
            for (int fm = 0; fm < 4; ++fm)
                #pragma unroll
                for (int fn = 0; fn < 4; ++fn)
                    acc[fm][fn] = __builtin_amdgcn_mfma_f32_16x16x32_bf16(af[fm], bfv[fn], acc[fm][fn], 0, 0, 0);
        }
        __syncthreads();   // taps0-4 done reading wc
        #pragma unroll
        for (int u = 0; u < 4; ++u) *(short8*)&wc[(u * 512 + tid) * 8] = stB[u];
        __syncthreads();   // wc(taps5-8) ready
        #pragma unroll
        for (int kk2 = 0; kk2 < 4; ++kk2) {
            const int kk = kk2 + 5;
            const int ky = kk / 3, kx = kk % 3;
            short8 af[4], bfv[4];
            #pragma unroll
            for (int fm = 0; fm < 4; ++fm)
                af[fm] = *(const short8*)&wc[((kk2 * 4 + kg) * 128 + wm * 64 + fm * 16 + l15) * 8];
            #pragma unroll
            for (int fn = 0; fn < 4; ++fn) {
                int n = wn * 64 + fn * 16 + l15;
                int r = (n >> 7) + ky, c = (n & 127) + kx;
                bfv[fn] = *(const short8*)&inT[(r * 130 + c) * 40 + kg * 8];
            }
            #pragma unroll
            for (int fm = 0; fm < 4; ++fm)
                #pragma unroll
                for (int fn = 0; fn < 4; ++fn)
                    acc[fm][fn] = __builtin_amdgcn_mfma_f32_16x16x32_bf16(af[fm], bfv[fn], acc[fm][fn], 0, 0, 0);
        }
        __syncthreads();   // protect inT/wc rewrite in next cc
    }

    // ---- epilogue: bias, store bf16, stats ----
    #pragma unroll
    for (int fm = 0; fm < 4; ++fm) {
        #pragma unroll
        for (int r = 0; r < 4; ++r) {
            const int co = wm * 64 + fm * 16 + kg * 4 + r;
            const float bb = b2[co];
            float ls = 0.f, lq = 0.f;
            #pragma unroll
            for (int fn = 0; fn < 4; ++fn) {
                float v = acc[fm][fn][r] + bb;
                ls += v; lq += v * v;
                int n = wn * 64 + fn * 16 + l15;
                y2[(((size_t)b * C1_ + co) * H_ + (y0 + (n >> 7))) * W_ + (n & 127)] = __float2bfloat16(v);
            }
            #pragma unroll
            for (int m = 1; m < 16; m <<= 1) {
                ls += __shfl_xor(ls, m, 64);
                lq += __shfl_xor(lq, m, 64);
            }
            if (l15 == 0) { atomicAdd(&redS[co], ls); atomicAdd(&redQ[co], lq); }
        }
    }
    __syncthreads();
    if (tid < 128) { atomicAdd(&sum2[tid], redS[tid]); atomicAdd(&sq2[tid], redQ[tid]); }
}

// ---------------- lateral path: maxpool2 + conv3x3(2->2) pad1 ----------------
__global__ __launch_bounds__(256) void poolconv_k(const float* __restrict__ out5,
                                                  const float* __restrict__ wl,
                                                  const float* __restrict__ bl,
                                                  float* __restrict__ ds) {
    int idx = blockIdx.x * 256 + threadIdx.x;
    int j = idx & 63;
    int i = (idx >> 6) & 63;
    int c = (idx >> 12) & 1;
    int b = idx >> 13;
    float acc = bl[c];
    #pragma unroll
    for (int ci = 0; ci < 2; ++ci) {
        const float* in = out5 + ((size_t)b * 5 + ci) * HW_;
        #pragma unroll
        for (int ky = 0; ky < 3; ++ky) {
            int ii = i + ky - 1;
            if (ii < 0 || ii > 63) continue;
            #pragma unroll
            for (int kx = 0; kx < 3; ++kx) {
                int jj = j + kx - 1;
                if (jj < 0 || jj > 63) continue;
                const float* p = in + (2 * ii) * W_ + 2 * jj;
                float pooled = fmaxf(fmaxf(p[0], p[1]), fmaxf(p[W_], p[W_ + 1]));
                acc += pooled * wl[(c * 2 + ci) * 9 + ky * 3 + kx];
            }
        }
    }
    ds[idx] = acc;
}

// ---------------- final: conv1x1(BN2+ReLU) + upsample + softmax + sigmoids ----------------
__global__ __launch_bounds__(256) void final_k(const float* __restrict__ out5,
                                               const __hip_bfloat16* __restrict__ y2,
                                               const float* __restrict__ s2,
                                               const float* __restrict__ t2,
                                               const float* __restrict__ w3,
                                               const float* __restrict__ b3,
                                               const float* __restrict__ dsb,
                                               float* __restrict__ out) {
    __shared__ float w3s[256], s2s[128], t2s[128];
    int tid = threadIdx.x;
    w3s[tid] = w3[tid];
    if (tid < 128) { s2s[tid] = s2[tid]; t2s[tid] = t2[tid]; }
    __syncthreads();
    int gid = blockIdx.x * 256 + tid;
    int b = gid >> 11;
    int rem = gid & 2047;
    int y = rem >> 4;
    int x0 = (rem & 15) * 8;
    int p = y * W_ + x0;

    const unsigned short* yp = (const unsigned short*)y2 + (size_t)b * C1_ * HW_ + p;
    float jm0[8], jm1[8];
    #pragma unroll
    for (int i = 0; i < 8; ++i) { jm0[i] = b3[0]; jm1[i] = b3[1]; }
    for (int ci = 0; ci < 128; ++ci) {
        short8 v = *(const short8*)(yp + (size_t)ci * HW_);
        float sc = s2s[ci], tc = t2s[ci];
        float w0 = w3s[ci], w1c = w3s[128 + ci];
        #pragma unroll
        for (int i = 0; i < 8; ++i) {
            union { unsigned int ui; float f; } cv;
            cv.ui = ((unsigned)(unsigned short)v[i]) << 16;
            float h = fmaxf(fmaf(sc, cv.f, tc), 0.f);
            jm0[i] = fmaf(h, w0, jm0[i]);
            jm1[i] = fmaf(h, w1c, jm1[i]);
        }
    }

    const float fo = (float)(63.0 / 127.0);
    float sy = (float)y * fo;
    int ly = (int)floorf(sy); ly = ly < 0 ? 0 : (ly > 62 ? 62 : ly);
    float wy = sy - (float)ly;
    const float* dbase = dsb + ((size_t)b * 2) * 4096;
    #pragma unroll
    for (int i = 0; i < 8; ++i) {
        int x = x0 + i;
        float sx = (float)x * fo;
        int lx = (int)floorf(sx); lx = lx < 0 ? 0 : (lx > 62 ? 62 : lx);
        float wx = sx - (float)lx;
        float up[2];
        #pragma unroll
        for (int c = 0; c < 2; ++c) {
            const float* d = dbase + c * 4096;
            float d00 = d[ly * 64 + lx],       d01 = d[ly * 64 + lx + 1];
            float d10 = d[(ly + 1) * 64 + lx], d11 = d[(ly + 1) * 64 + lx + 1];
            up[c] = (1.f - wy) * ((1.f - wx) * d00 + wx * d01) + wy * ((1.f - wx) * d10 + wx * d11);
        }
        float dlt = (jm1[i] + up[1]) - (jm0[i] + up[0]);
        out[(size_t)b * HW_ + p + i] = 1.f / (1.f + expf(-dlt));
    }
    #pragma unroll
    for (int i = 0; i < 8; ++i) {
        float lm = out5[((size_t)b * 5 + 2) * HW_ + p + i];
        out[524288 + (size_t)b * HW_ + p + i] = 1.f / (1.f + expf(-lm));
    }
    #pragma unroll
    for (int i = 0; i < 8; ++i) {
        float o3 = out5[((size_t)b * 5 + 3) * HW_ + p + i];
        float o4 = out5[((size_t)b * 5 + 4) * HW_ + p + i];
        out[1048576 + ((size_t)b * 2 + 0) * HW_ + p + i] = 1.f / (1.f + expf(-o3)) - 0.5f;
        out[1048576 + ((size_t)b * 2 + 1) * HW_ + p + i] = 1.f / (1.f + expf(-o4)) - 0.5f;
    }
}

extern "C" void kernel_launch(void* const* d_in, const int* in_sizes, int n_in,
                              void* d_out, int out_size, void* d_ws, size_t ws_size,
                              hipStream_t stream) {
    const float* out5 = (const float*)d_in[0];
    const float* jmap = (const float*)d_in[1];
    const float* w1   = (const float*)d_in[2];
    const float* b1   = (const float*)d_in[3];
    const float* g1   = (const float*)d_in[4];
    const float* be1  = (const float*)d_in[5];
    const float* w2   = (const float*)d_in[6];
    const float* b2   = (const float*)d_in[7];
    const float* g2   = (const float*)d_in[8];
    const float* be2  = (const float*)d_in[9];
    const float* w3   = (const float*)d_in[10];
    const float* b3   = (const float*)d_in[11];
    const float* wl   = (const float*)d_in[12];
    const float* bl   = (const float*)d_in[13];
    const float* ga   = (const float*)d_in[14];
    const float* gb   = (const float*)d_in[15];
    float* out = (float*)d_out;

    // ws layout (~135.3 MB):
    //   [0, 134217728)                 y2 bf16
    //   [134217728, +294912)           w2t2 (conv2 weights, bf16)  } overlapped later by
    //   [134512640, +8192)             w1t  (conv1 weights, bf16)  } dsb (disjoint lifetime)
    //   [134217728, +1048576)          dsb  (poolconv out, written after conv2 done)
    //   [135266304, +4096)             stats
    char* ws = (char*)d_ws;
    __hip_bfloat16* y2 = (__hip_bfloat16*)ws;
    unsigned short* w2t2 = (unsigned short*)(ws + 134217728);
    unsigned short* w1t  = (unsigned short*)(ws + 134512640);
    float* dsb = (float*)(ws + 134217728);
    float* st  = (float*)(ws + 135266304);
    float* sum1 = st;        float* sq1 = st + 128;
    float* sum2 = st + 256;  float* sq2 = st + 384;
    float* s1 = st + 512;    float* t1 = st + 640;
    float* s2 = st + 768;    float* t2 = st + 896;

    float* gtmp = out + 2097152;   // gauss region doubles as vertical-pass temp

    zero_k<<<1, 512, 0, stream>>>(st);
    prep_w2t2<<<576, 256, 0, stream>>>(w2, w2t2);
    prep_w1t<<<16, 256, 0, stream>>>(w1, w1t);
    gauss_v<<<dim3(64, 32), 256, 0, stream>>>(jmap, gtmp, ga, gb);
    gauss_h<<<dim3(64, 32), 256, 0, stream>>>(jmap, gtmp, ga, gb);
    conv1stats_k<<<dim3(16, 32), 256, 0, stream>>>(out5, w1, b1, sum1, sq1);
    bnp_k<<<1, 128, 0, stream>>>(sum1, sq1, g1, be1, s1, t1);
    conv2_mfma<<<2048, 512, 0, stream>>>(out5, b1, s1, t1, w2t2, w1t, b2, y2, sum2, sq2);
    bnp_k<<<1, 128, 0, stream>>>(sum2, sq2, g2, be2, s2, t2);
    poolconv_k<<<1024, 256, 0, stream>>>(out5, wl, bl, dsb);
    final_k<<<256, 256, 0, stream>>>(out5, y2, s2, t2, w3, b3, dsb, out);
}

// Round 6
// 377.367 us; speedup vs baseline: 11.1107x; 1.1572x over previous
//
#include <hip/hip_runtime.h>
#include <hip/hip_bf16.h>

#define B_   32
#define H_   128
#define W_   128
#define HW_  16384
#define C1_  128

typedef __attribute__((ext_vector_type(8))) short short8;
typedef __attribute__((ext_vector_type(4))) short short4v;
typedef __attribute__((ext_vector_type(4))) float f32x4;
typedef __attribute__((ext_vector_type(2))) float f32x2;

static __device__ __forceinline__ unsigned short bfbits(float f) {
    __hip_bfloat16 h = __float2bfloat16(f);
    return *reinterpret_cast<unsigned short*>(&h);
}
static __device__ __forceinline__ float bf2f(unsigned int u) {
    union { unsigned int ui; float f; } cv; cv.ui = u << 16; return cv.f;
}

// ---------------- zero stats ----------------
__global__ void zero_k(float* p) { p[threadIdx.x] = 0.f; }

// ---- weight prep: w2[co][ci][kk] f32 -> w2t2[cc][kk][kg][co][8] bf16 (147456 shorts) ----
__global__ __launch_bounds__(256) void prep_w2t2(const float* __restrict__ w2,
                                                 unsigned short* __restrict__ w2t2) {
    int idx = blockIdx.x * 256 + threadIdx.x;
    if (idx >= 147456) return;
    int e  = idx & 7;
    int co = (idx >> 3) & 127;
    int kg = (idx >> 10) & 3;
    int t  = idx >> 12;          // 0..35
    int kk = t % 9, cc = t / 9;
    int ci = cc * 32 + kg * 8 + e;
    w2t2[idx] = bfbits(w2[((size_t)co * 128 + ci) * 9 + kk]);
}

// ---- weight prep: w1[ci][18] f32 -> w1t[ci][32] bf16, zero-padded K 18..31 ----
__global__ __launch_bounds__(256) void prep_w1t(const float* __restrict__ w1,
                                                unsigned short* __restrict__ w1t) {
    int idx = blockIdx.x * 256 + threadIdx.x;
    if (idx >= 4096) return;
    int k = idx & 31, ci = idx >> 5;
    w1t[idx] = (k < 18) ? bfbits(w1[ci * 18 + k]) : (unsigned short)0;
}

// ---------------- gaussian splat: vertical pass (±16 window; tail < 3e-14) ----------------
__global__ __launch_bounds__(256) void gauss_v(const float* __restrict__ jmap,
                                               float* __restrict__ gtmp,
                                               const float* __restrict__ ga,
                                               const float* __restrict__ gb) {
    __shared__ float k1[255];
    float a = ga[0] / (gb[0] * gb[0]);
    for (int i = threadIdx.x; i < 255; i += 256) {
        float d = (float)(i - 127);
        k1[i] = expf(a * d * d);
    }
    __syncthreads();
    int b = blockIdx.y;
    int y = blockIdx.x * 2 + (threadIdx.x >> 7);
    int x = threadIdx.x & 127;
    const float* m = jmap + (size_t)b * HW_;
    int lo = y - 16; if (lo < 0) lo = 0;
    int hi = y + 16; if (hi > 127) hi = 127;
    float s = 0.f;
    for (int yy = lo; yy <= hi; ++yy) {
        float mv = m[yy * W_ + x];
        s += (mv == 1.0f) ? k1[yy - y + 127] : 0.f;
    }
    gtmp[(size_t)b * HW_ + y * W_ + x] = s;
}

// ---------------- gaussian splat: horizontal pass + finalize (in-place) ----------------
__global__ __launch_bounds__(256) void gauss_h(const float* __restrict__ jmap,
                                               float* __restrict__ gtmp,
                                               const float* __restrict__ ga,
                                               const float* __restrict__ gb) {
    __shared__ float k1[255];
    __shared__ float row[256];
    float a = ga[0] / (gb[0] * gb[0]);
    for (int i = threadIdx.x; i < 255; i += 256) {
        float d = (float)(i - 127);
        k1[i] = expf(a * d * d);
    }
    int b = blockIdx.y;
    int y0 = blockIdx.x * 2;
    int tid = threadIdx.x;
    row[tid] = gtmp[(size_t)b * HW_ + (y0 + (tid >> 7)) * W_ + (tid & 127)];
    __syncthreads();
    int y = y0 + (tid >> 7);
    int x = tid & 127;
    int base = (tid >> 7) * 128;
    int lo = x - 16; if (lo < 0) lo = 0;
    int hi = x + 16; if (hi > 127) hi = 127;
    float s = 0.f;
    for (int xx = lo; xx <= hi; ++xx)
        s += k1[xx - x + 127] * row[base + xx];
    float g = jmap[(size_t)b * HW_ + y * W_ + x] + s;
    g = (g <= 0.05f) ? 0.f : fminf(g, 1.0f);
    gtmp[(size_t)b * HW_ + y * W_ + x] = g;
}

// ---------------- conv1 stats only (exact f32) ----------------
__global__ __launch_bounds__(256) void conv1stats_k(const float* __restrict__ out5,
                                                    const float* __restrict__ w1,
                                                    const float* __restrict__ b1,
                                                    float* __restrict__ sum1,
                                                    float* __restrict__ sq1) {
    int cg = blockIdx.x;
    int b  = blockIdx.y;
    int tid = threadIdx.x;
    __shared__ float wsh[8][18];
    __shared__ float bsh[8];
    __shared__ float red[256];
    for (int i = tid; i < 144; i += 256) wsh[i / 18][i % 18] = w1[cg * 8 * 18 + i];
    if (tid < 8) bsh[tid] = b1[cg * 8 + tid];
    __syncthreads();
    float ls[8], lq[8];
    #pragma unroll
    for (int i = 0; i < 8; ++i) { ls[i] = 0.f; lq[i] = 0.f; }
    const float* in0 = out5 + (size_t)b * 5 * HW_;
    const float* in1 = in0 + HW_;
    for (int pos = tid; pos < HW_; pos += 256) {
        int y = pos >> 7, x = pos & 127;
        float v0[9], v1[9];
        #pragma unroll
        for (int ky = 0; ky < 3; ++ky)
            #pragma unroll
            for (int kx = 0; kx < 3; ++kx) {
                int yy = y + ky - 1, xx = x + kx - 1;
                bool ok = ((unsigned)yy < 128u) && ((unsigned)xx < 128u);
                v0[ky * 3 + kx] = ok ? in0[yy * W_ + xx] : 0.f;
                v1[ky * 3 + kx] = ok ? in1[yy * W_ + xx] : 0.f;
            }
        #pragma unroll
        for (int i = 0; i < 8; ++i) {
            float a = bsh[i];
            #pragma unroll
            for (int k = 0; k < 9; ++k) a += v0[k] * wsh[i][k] + v1[k] * wsh[i][9 + k];
            ls[i] += a; lq[i] += a * a;
        }
    }
    for (int i = 0; i < 8; ++i) {
        red[tid] = ls[i]; __syncthreads();
        for (int s = 128; s > 0; s >>= 1) { if (tid < s) red[tid] += red[tid + s]; __syncthreads(); }
        if (tid == 0) atomicAdd(&sum1[cg * 8 + i], red[0]);
        __syncthreads();
        red[tid] = lq[i]; __syncthreads();
        for (int s = 128; s > 0; s >>= 1) { if (tid < s) red[tid] += red[tid + s]; __syncthreads(); }
        if (tid == 0) atomicAdd(&sq1[cg * 8 + i], red[0]);
        __syncthreads();
    }
}

// ---------------- BN params ----------------
__global__ void bnp_k(const float* __restrict__ sum, const float* __restrict__ sq,
                      const float* __restrict__ gamma, const float* __restrict__ beta,
                      float* __restrict__ s, float* __restrict__ t) {
    int c = threadIdx.x;
    const float N = (float)(B_ * HW_);
    float m = sum[c] / N;
    float v = sq[c] / N - m * m;
    float sc = gamma[c] / sqrtf(v + 1e-5f);
    s[c] = sc;
    t[c] = beta[c] - sc * m;
}

// ---------------- conv2 via MFMA: 1024-thr block, co128 x pos512 (4 rows) ----------------
// 16 waves: wm = w&1 (co half), wn = w>>1 (pos 64-group). 2 barriers per ci-chunk.
// h1 B-frags prebuilt in registers from global; wc staged via global_load_lds.
__global__ __launch_bounds__(1024) void conv2_mfma(
    const float* __restrict__ out5,
    const float* __restrict__ b1,
    const float* __restrict__ s1,
    const float* __restrict__ t1,
    const unsigned short* __restrict__ w2t2,
    const unsigned short* __restrict__ w1t,
    const float* __restrict__ b2,
    __hip_bfloat16* __restrict__ y2,
    float* __restrict__ sum2,
    float* __restrict__ sq2)
{
    __shared__ unsigned short inT[31200];   // h1: [r*130+c][40] (6 rows), 62400 B
    __shared__ unsigned short wc[36864];    // all 9 taps of one cc, 73728 B; reused as pt
    __shared__ unsigned short w1l[4096];    // conv1 weights [ci][32], 8192 B
    __shared__ float s1sh[128], t1sh[128], redS[128], redQ[128];

    const int tid = threadIdx.x;
    const int b  = blockIdx.x >> 5;
    const int y0 = (blockIdx.x & 31) * 4;
    const int lane = tid & 63, w = tid >> 6;   // w 0..15
    const int wm = w & 1, wn = w >> 1;         // co half / pos 64-group
    const int l15 = lane & 15, kg = lane >> 4;

    if (tid < 128) {
        redS[tid] = 0.f; redQ[tid] = 0.f;
        float sv = s1[tid]; s1sh[tid] = sv;
        t1sh[tid] = fmaf(sv, b1[tid], t1[tid]);   // fold conv1 bias into BN shift
    }
    if (tid < 512) *(short8*)&w1l[tid * 8] = *(const short8*)&w1t[tid * 8];

    // ---- prebuild h1 im2col B-fragments in registers (once) ----
    const float* in0 = out5 + (size_t)b * 5 * HW_;
    const float* in1 = in0 + HW_;
    const int mi  = wm;        // wave's conv1 ci-half
    const int njb = w >> 1;    // base position-tile
    short8 bfrag[7];
    #pragma unroll
    for (int k = 0; k < 7; ++k) {
        short8 f = (short8){0,0,0,0,0,0,0,0};
        int nj = njb + k * 8;
        int q  = nj * 16 + l15;
        if (nj <= 48 && q < 780) {
            int r = q / 130, c = q - r * 130;
            int gy = y0 - 1 + r, gx = c - 1;
            #pragma unroll
            for (int kk = 0; kk < 8; ++kk) {
                int kidx = kg * 8 + kk;
                unsigned short v = 0;
                if (kidx < 18) {
                    int ch = (kidx >= 9) ? 1 : 0;
                    int km = kidx - ch * 9;
                    int ky = km / 3, kx = km - ky * 3;
                    int yy = gy + ky - 1, xx = gx + kx - 1;
                    if ((unsigned)yy < 128u && (unsigned)xx < 128u)
                        v = bfbits((ch ? in1 : in0)[yy * W_ + xx]);
                }
                f[kk] = (short)v;
            }
        }
        bfrag[k] = f;
    }
    __syncthreads();   // w1l / s1sh / red zero visible

    f32x4 acc[4][4];
    #pragma unroll
    for (int fm = 0; fm < 4; ++fm)
        #pragma unroll
        for (int fn = 0; fn < 4; ++fn) acc[fm][fn] = (f32x4){0.f, 0.f, 0.f, 0.f};

    for (int cc = 0; cc < 4; ++cc) {
        // async stage all 9 taps' weights for this cc into wc (drained by next barrier)
        const unsigned short* wsrc = w2t2 + cc * 36864;
        #pragma unroll
        for (int u = 0; u < 4; ++u)
            __builtin_amdgcn_global_load_lds(
                (const unsigned int*)(wsrc + (u * 1024 + tid) * 8),
                (unsigned int*)&wc[(u * 1024 + tid) * 8], 16, 0, 0);
        if (tid < 512)
            __builtin_amdgcn_global_load_lds(
                (const unsigned int*)(wsrc + (4096 + tid) * 8),
                (unsigned int*)&wc[(4096 + tid) * 8], 16, 0, 0);

        // ---- h1 chunk via MFMA from register B-frags ----
        short8 a1 = *(const short8*)&w1l[(cc * 32 + mi * 16 + l15) * 32 + kg * 8];
        #pragma unroll
        for (int k = 0; k < 7; ++k) {
            int nj = njb + k * 8;
            if (nj <= 48) {
                int q = nj * 16 + l15;
                f32x4 hacc = (f32x4){0.f, 0.f, 0.f, 0.f};
                hacc = __builtin_amdgcn_mfma_f32_16x16x32_bf16(a1, bfrag[k], hacc, 0, 0, 0);
                int r = q / 130, c = q - r * 130;
                int gy = y0 - 1 + r;
                bool zero = (q >= 780) || ((unsigned)gy >= 128u) || (c == 0) || (c == 129);
                short4v hv;
                #pragma unroll
                for (int rr = 0; rr < 4; ++rr) {
                    int cig = cc * 32 + mi * 16 + kg * 4 + rr;
                    float h = fmaxf(fmaf(s1sh[cig], hacc[rr], t1sh[cig]), 0.f);
                    hv[rr] = zero ? (short)0 : (short)bfbits(h);
                }
                if (q < 780)
                    *(short4v*)&inT[(r * 130 + c) * 40 + mi * 16 + kg * 4] = hv;
            }
        }
        __syncthreads();   // inT written, wc DMA drained

        // ---- conv2: 9 taps x 16 MFMA per wave ----
        #pragma unroll
        for (int kk = 0; kk < 9; ++kk) {
            const int ky = kk / 3, kx = kk % 3;
            short8 af[4], bfv[4];
            #pragma unroll
            for (int fm = 0; fm < 4; ++fm)
                af[fm] = *(const short8*)&wc[((kk * 4 + kg) * 128 + wm * 64 + fm * 16 + l15) * 8];
            #pragma unroll
            for (int fn = 0; fn < 4; ++fn) {
                int n = wn * 64 + fn * 16 + l15;
                int r = (n >> 7) + ky, c2 = (n & 127) + kx;
                bfv[fn] = *(const short8*)&inT[(r * 130 + c2) * 40 + kg * 8];
            }
            #pragma unroll
            for (int fm = 0; fm < 4; ++fm)
                #pragma unroll
                for (int fn = 0; fn < 4; ++fn)
                    acc[fm][fn] = __builtin_amdgcn_mfma_f32_16x16x32_bf16(af[fm], bfv[fn], acc[fm][fn], 0, 0, 0);
        }
        __syncthreads();   // wc/inT reads done before next cc rewrites
    }

    // ---- epilogue: stats + coalesced y2 via LDS repack (pt = wc region) ----
    unsigned short* pt = wc;
    #pragma unroll
    for (int fm = 0; fm < 4; ++fm) {
        #pragma unroll
        for (int r = 0; r < 4; ++r) {
            const int col = fm * 16 + kg * 4 + r;
            const int co  = wm * 64 + col;
            const float bb = b2[co];
            float ls = 0.f, lq = 0.f;
            #pragma unroll
            for (int fn = 0; fn < 4; ++fn) {
                float v = acc[fm][fn][r] + bb;
                ls += v; lq += v * v;
            }
            #pragma unroll
            for (int m = 1; m < 16; m <<= 1) {
                ls += __shfl_xor(ls, m, 64);
                lq += __shfl_xor(lq, m, 64);
            }
            if (l15 == 0) { atomicAdd(&redS[co], ls); atomicAdd(&redQ[co], lq); }
        }
    }
    if (wm == 0) {
        #pragma unroll
        for (int fm = 0; fm < 4; ++fm)
            #pragma unroll
            for (int r = 0; r < 4; ++r) {
                const int col = fm * 16 + kg * 4 + r;
                const float bb = b2[col];
                const int xr = ((col >> 2) & 3) << 4;
                #pragma unroll
                for (int fn = 0; fn < 4; ++fn) {
                    int n = wn * 64 + fn * 16 + l15;
                    pt[col * 512 + (n ^ xr)] = bfbits(acc[fm][fn][r] + bb);
                }
            }
    }
    __syncthreads();
    if (tid < 128) { atomicAdd(&sum2[tid], redS[tid]); atomicAdd(&sq2[tid], redQ[tid]); }
    {
        unsigned short* y2u = (unsigned short*)y2;
        int co_l = tid >> 4, sub = tid & 15;
        int xr = ((co_l >> 2) & 3) << 4;
        size_t base = (((size_t)b * C1_ + co_l) * H_ + y0) * (size_t)W_ + sub * 8;
        #pragma unroll
        for (int j = 0; j < 4; ++j) {
            int p = j * 128 + sub * 8;
            *(short8*)&y2u[base + (size_t)j * W_] = *(short8*)&pt[co_l * 512 + (p ^ xr)];
        }
    }
    __syncthreads();
    if (wm == 1) {
        #pragma unroll
        for (int fm = 0; fm < 4; ++fm)
            #pragma unroll
            for (int r = 0; r < 4; ++r) {
                const int col = fm * 16 + kg * 4 + r;
                const float bb = b2[64 + col];
                const int xr = ((col >> 2) & 3) << 4;
                #pragma unroll
                for (int fn = 0; fn < 4; ++fn) {
                    int n = wn * 64 + fn * 16 + l15;
                    pt[col * 512 + (n ^ xr)] = bfbits(acc[fm][fn][r] + bb);
                }
            }
    }
    __syncthreads();
    {
        unsigned short* y2u = (unsigned short*)y2;
        int co_l = tid >> 4, sub = tid & 15;
        int xr = ((co_l >> 2) & 3) << 4;
        size_t base = (((size_t)b * C1_ + 64 + co_l) * H_ + y0) * (size_t)W_ + sub * 8;
        #pragma unroll
        for (int j = 0; j < 4; ++j) {
            int p = j * 128 + sub * 8;
            *(short8*)&y2u[base + (size_t)j * W_] = *(short8*)&pt[co_l * 512 + (p ^ xr)];
        }
    }
}

// ---------------- lateral path: maxpool2 + conv3x3(2->2) pad1 ----------------
__global__ __launch_bounds__(256) void poolconv_k(const float* __restrict__ out5,
                                                  const float* __restrict__ wl,
                                                  const float* __restrict__ bl,
                                                  float* __restrict__ ds) {
    int idx = blockIdx.x * 256 + threadIdx.x;
    int j = idx & 63;
    int i = (idx >> 6) & 63;
    int c = (idx >> 12) & 1;
    int b = idx >> 13;
    float acc = bl[c];
    #pragma unroll
    for (int ci = 0; ci < 2; ++ci) {
        const float* in = out5 + ((size_t)b * 5 + ci) * HW_;
        #pragma unroll
        for (int ky = 0; ky < 3; ++ky) {
            int ii = i + ky - 1;
            if (ii < 0 || ii > 63) continue;
            #pragma unroll
            for (int kx = 0; kx < 3; ++kx) {
                int jj = j + kx - 1;
                if (jj < 0 || jj > 63) continue;
                const float* p = in + (2 * ii) * W_ + 2 * jj;
                float pooled = fmaxf(fmaxf(p[0], p[1]), fmaxf(p[W_], p[W_ + 1]));
                acc += pooled * wl[(c * 2 + ci) * 9 + ky * 3 + kx];
            }
        }
    }
    ds[idx] = acc;
}

// ---------------- final: conv1x1(BN2+ReLU) + upsample + softmax + sigmoids, 2 px/thr ----
__global__ __launch_bounds__(256) void final_k(const float* __restrict__ out5,
                                               const __hip_bfloat16* __restrict__ y2,
                                               const float* __restrict__ s2,
                                               const float* __restrict__ t2,
                                               const float* __restrict__ w3,
                                               const float* __restrict__ b3,
                                               const float* __restrict__ dsb,
                                               float* __restrict__ out) {
    __shared__ float w3s[256], s2s[128], t2s[128];
    int tid = threadIdx.x;
    w3s[tid] = w3[tid];
    if (tid < 128) { s2s[tid] = s2[tid]; t2s[tid] = t2[tid]; }
    __syncthreads();
    int gid = blockIdx.x * 256 + tid;       // 262144 = 32*128*64
    int b = gid >> 13;
    int rem = gid & 8191;
    int y = rem >> 6;
    int x0 = (rem & 63) * 2;
    int p = y * W_ + x0;

    const unsigned short* yp = (const unsigned short*)y2 + (size_t)b * C1_ * HW_ + p;
    float jm0a = b3[0], jm1a = b3[1], jm0b = b3[0], jm1b = b3[1];
    for (int ci = 0; ci < 128; ++ci) {
        unsigned int v = *(const unsigned int*)(yp + (size_t)ci * HW_);
        float sc = s2s[ci], tc = t2s[ci];
        float w0 = w3s[ci], w1c = w3s[128 + ci];
        float h0 = fmaxf(fmaf(sc, bf2f(v & 0xffffu), tc), 0.f);
        float h1 = fmaxf(fmaf(sc, bf2f(v >> 16), tc), 0.f);
        jm0a = fmaf(h0, w0, jm0a); jm1a = fmaf(h0, w1c, jm1a);
        jm0b = fmaf(h1, w0, jm0b); jm1b = fmaf(h1, w1c, jm1b);
    }

    const float fo = (float)(63.0 / 127.0);
    float sy = (float)y * fo;
    int ly = (int)floorf(sy); ly = ly < 0 ? 0 : (ly > 62 ? 62 : ly);
    float wy = sy - (float)ly;
    const float* dbase = dsb + ((size_t)b * 2) * 4096;
    float sig[2];
    float jm0[2] = {jm0a, jm0b}, jm1[2] = {jm1a, jm1b};
    #pragma unroll
    for (int i = 0; i < 2; ++i) {
        int x = x0 + i;
        float sx = (float)x * fo;
        int lx = (int)floorf(sx); lx = lx < 0 ? 0 : (lx > 62 ? 62 : lx);
        float wx = sx - (float)lx;
        float up[2];
        #pragma unroll
        for (int c = 0; c < 2; ++c) {
            const float* d = dbase + c * 4096;
            float d00 = d[ly * 64 + lx],       d01 = d[ly * 64 + lx + 1];
            float d10 = d[(ly + 1) * 64 + lx], d11 = d[(ly + 1) * 64 + lx + 1];
            up[c] = (1.f - wy) * ((1.f - wx) * d00 + wx * d01) + wy * ((1.f - wx) * d10 + wx * d11);
        }
        float dlt = (jm1[i] + up[1]) - (jm0[i] + up[0]);
        sig[i] = 1.f / (1.f + expf(-dlt));
    }
    *(f32x2*)&out[(size_t)b * HW_ + p] = (f32x2){sig[0], sig[1]};

    float lm0 = out5[((size_t)b * 5 + 2) * HW_ + p];
    float lm1 = out5[((size_t)b * 5 + 2) * HW_ + p + 1];
    *(f32x2*)&out[524288 + (size_t)b * HW_ + p] =
        (f32x2){1.f / (1.f + expf(-lm0)), 1.f / (1.f + expf(-lm1))};

    float o30 = out5[((size_t)b * 5 + 3) * HW_ + p];
    float o31 = out5[((size_t)b * 5 + 3) * HW_ + p + 1];
    float o40 = out5[((size_t)b * 5 + 4) * HW_ + p];
    float o41 = out5[((size_t)b * 5 + 4) * HW_ + p + 1];
    *(f32x2*)&out[1048576 + ((size_t)b * 2 + 0) * HW_ + p] =
        (f32x2){1.f / (1.f + expf(-o30)) - 0.5f, 1.f / (1.f + expf(-o31)) - 0.5f};
    *(f32x2*)&out[1048576 + ((size_t)b * 2 + 1) * HW_ + p] =
        (f32x2){1.f / (1.f + expf(-o40)) - 0.5f, 1.f / (1.f + expf(-o41)) - 0.5f};
}

extern "C" void kernel_launch(void* const* d_in, const int* in_sizes, int n_in,
                              void* d_out, int out_size, void* d_ws, size_t ws_size,
                              hipStream_t stream) {
    const float* out5 = (const float*)d_in[0];
    const float* jmap = (const float*)d_in[1];
    const float* w1   = (const float*)d_in[2];
    const float* b1   = (const float*)d_in[3];
    const float* g1   = (const float*)d_in[4];
    const float* be1  = (const float*)d_in[5];
    const float* w2   = (const float*)d_in[6];
    const float* b2   = (const float*)d_in[7];
    const float* g2   = (const float*)d_in[8];
    const float* be2  = (const float*)d_in[9];
    const float* w3   = (const float*)d_in[10];
    const float* b3   = (const float*)d_in[11];
    const float* wl   = (const float*)d_in[12];
    const float* bl   = (const float*)d_in[13];
    const float* ga   = (const float*)d_in[14];
    const float* gb   = (const float*)d_in[15];
    float* out = (float*)d_out;

    // ws layout (~135.3 MB):
    //   [0, 134217728)           y2 bf16
    //   [134217728, +294912)     w2t2 } overlapped later by dsb (disjoint lifetimes)
    //   [134512640, +8192)       w1t  }
    //   [134217728, +1048576)    dsb (poolconv out; written after conv2 done)
    //   [135266304, +4096)       stats
    char* ws = (char*)d_ws;
    __hip_bfloat16* y2 = (__hip_bfloat16*)ws;
    unsigned short* w2t2 = (unsigned short*)(ws + 134217728);
    unsigned short* w1t  = (unsigned short*)(ws + 134512640);
    float* dsb = (float*)(ws + 134217728);
    float* st  = (float*)(ws + 135266304);
    float* sum1 = st;        float* sq1 = st + 128;
    float* sum2 = st + 256;  float* sq2 = st + 384;
    float* s1 = st + 512;    float* t1 = st + 640;
    float* s2 = st + 768;    float* t2 = st + 896;

    float* gtmp = out + 2097152;   // gauss region doubles as vertical-pass temp

    zero_k<<<1, 512, 0, stream>>>(st);
    prep_w2t2<<<576, 256, 0, stream>>>(w2, w2t2);
    prep_w1t<<<16, 256, 0, stream>>>(w1, w1t);
    gauss_v<<<dim3(64, 32), 256, 0, stream>>>(jmap, gtmp, ga, gb);
    gauss_h<<<dim3(64, 32), 256, 0, stream>>>(jmap, gtmp, ga, gb);
    conv1stats_k<<<dim3(16, 32), 256, 0, stream>>>(out5, w1, b1, sum1, sq1);
    bnp_k<<<1, 128, 0, stream>>>(sum1, sq1, g1, be1, s1, t1);
    conv2_mfma<<<1024, 1024, 0, stream>>>(out5, b1, s1, t1, w2t2, w1t, b2, y2, sum2, sq2);
    bnp_k<<<1, 128, 0, stream>>>(sum2, sq2, g2, be2, s2, t2);
    poolconv_k<<<1024, 256, 0, stream>>>(out5, wl, bl, dsb);
    final_k<<<1024, 256, 0, stream>>>(out5, y2, s2, t2, w3, b3, dsb, out);
}